// Round 1
// baseline (1157.810 us; speedup 1.0000x reference)
//
#include <hip/hip_runtime.h>
#include <hip/hip_fp16.h>

#define TT   2048
#define BB   64
#define II   16
#define HH   8
#define HIDN 64
#define GG   256   // 4*HIDN
#define T4   (TT / 4)

typedef _Float16 h2 __attribute__((ext_vector_type(2)));
typedef _Float16 h4 __attribute__((ext_vector_type(4)));
typedef _Float16 h8 __attribute__((ext_vector_type(8)));
typedef float    f4 __attribute__((ext_vector_type(4)));

__device__ __forceinline__ float fdot2(h2 a, h2 b, float c) {
    return __builtin_amdgcn_fdot2(a, b, c, false);
}
__device__ __forceinline__ float fast_sigmoid(float z) {
    return __builtin_amdgcn_rcpf(1.0f + __expf(-z));
}
__device__ __forceinline__ float fast_tanh(float z) {
    return fmaf(2.0f, __builtin_amdgcn_rcpf(1.0f + __expf(-2.0f * z)), -1.0f);
}

// Swizzled LDS byte offset for element (b, u) of a [16 b][64 u] f16 tile.
// 16B granules along u; granule index XOR b spreads the 8 granule-starts of a
// wave's ds_read_b128 (lanes: b=lane&15, u=(lane>>4)*8) across all bank pairs.
__device__ __forceinline__ int lds_off(int b, int u) {
    return b * 128 + ((((u >> 3) ^ b) & 7) << 4) + (u & 7) * 2;
}
__device__ __forceinline__ h8 cvt8(const float* p) {
    float4 v0 = ((const float4*)p)[0];
    float4 v1 = ((const float4*)p)[1];
    return h8{(_Float16)v0.x, (_Float16)v0.y, (_Float16)v0.z, (_Float16)v0.w,
              (_Float16)v1.x, (_Float16)v1.y, (_Float16)v1.z, (_Float16)v1.w};
}

// ---------------- x -> f16 conversion (one-time, trivial) ----------------
__global__ void cvt_x_kernel(const float* __restrict__ x, _Float16* __restrict__ xh, int n4) {
    int i = blockIdx.x * blockDim.x + threadIdx.x;
    if (i < n4) {
        float4 v = ((const float4*)x)[i];
        ((h2*)xh)[2 * i]     = h2{ (_Float16)v.x, (_Float16)v.y };
        ((h2*)xh)[2 * i + 1] = h2{ (_Float16)v.z, (_Float16)v.w };
    }
}

// ---------------- main recurrent kernel: MFMA-batched chains ----------------
// One 1024-thread block per (head, 16-batch group); grid = 32. All 16 chains
// of the group share W_hh, so z = W.h is one (256x64)@(64x16) matmul/step on
// the (previously idle) matrix pipe: 3 chained mfma_f32_16x16x32_f16
// (K-tiles: h[0:32], h[32:64], x zero-padded to 32; bias rides as C-input).
// W rows are permuted to r' = 4*u_local + g so the C fragment of lane
// (hi=lane>>4, bl=lane&15) is exactly {z_i,z_f,z_g,z_o} of unit 4w+hi, batch
// bl -> gates stay 1-per-lane (max elementwise parallelism, like the old
// kernel) with ZERO post-MFMA shuffling. h crosses waves via a 2KB
// double-buffered swizzled LDS tile; ONE barrier per step.
__global__ __launch_bounds__(1024)
void lstm_mfma(const _Float16* __restrict__ xh,
               const float* __restrict__ Wih,
               const float* __restrict__ Whh,
               const float* __restrict__ bih,
               const float* __restrict__ bhh,
               _Float16* __restrict__ stage_f16)   // [t4][chain][unit][4] h4 (same as old)
{
    const int tid  = threadIdx.x;
    const int w    = tid >> 6;          // wave 0..15: owns gate-rows 16w..16w+15
    const int lane = tid & 63;
    const int hi   = lane >> 4;         // k-group / C row-group
    const int bl   = lane & 15;         // batch-in-group (C col)
    const int hd   = blockIdx.x >> 2;
    const int bg   = blockIdx.x & 3;
    const int ue   = 4 * w + hi;        // this lane's hidden unit (elementwise side)

    // ---- A fragments, row-permuted: frag row r'(=lane&15) -> gate g=r'&3, unit 4w+(r'>>2)
    const int rA = hd * GG + (bl & 3) * HIDN + 4 * w + (bl >> 2);
    const float* pw = Whh + (size_t)rA * HIDN;
    h8 a0 = cvt8(pw + hi * 8);          // k = units (lane>>4)*8 + 0..7
    h8 a1 = cvt8(pw + 32 + hi * 8);     // k = units 32 + ...
    h8 a2{};                            // x-projection K-tile, zero-padded k>=16
    if (hi < 2) a2 = cvt8(Wih + (size_t)rA * II + hi * 8);

    // ---- bias as MFMA C-input (gate g = reg index, unit = ue, col = bl)
    f4 biasv;
#pragma unroll
    for (int g = 0; g < 4; ++g) {
        int r = hd * GG + g * HIDN + ue;
        biasv[g] = bih[r] + bhh[r];
    }

    // ---- LDS: h double-buffer + x^T double-buffer (zero-padded to 64 u) ----
    __shared__ __align__(16) char hA[2048];
    __shared__ __align__(16) char hB[2048];
    __shared__ __align__(16) char xA[2048];
    __shared__ __align__(16) char xB[2048];

    const int off_b0 = lds_off(bl, hi * 8);        // B frag, k-tile 0 (also x tile)
    const int off_b1 = lds_off(bl, 32 + hi * 8);   // B frag, k-tile 1
    const int off_hw = lds_off(bl, ue);            // h(t) write slot
    const int off_xw = lds_off(bl, 4 * hi);        // x stage write (u = 4*hi < 16)

    // prologue: zero x buffers (pad region stays 0 forever), zero h(-1)
    if (tid < 512) ((unsigned int*)xA)[tid] = 0u;
    else           ((unsigned int*)xB)[tid - 512] = 0u;
    *(_Float16*)(hA + off_hw) = (_Float16)0.0f;
    __syncthreads();
    const _Float16* xrow = xh + (size_t)(bg * 16 + bl) * II + 4 * hi;
    if (w == 0) {                                  // stage x(0)
        h4 xv = *(const h4*)xrow;
        *(h4*)(xA + off_xw) = xv;
    }
    __syncthreads();

    float cst = 0.0f;
    h4* sptr = (h4*)stage_f16 + (size_t)(hd * 64 + bg * 16 + bl) * 64 + ue;

#define STEP(jj, CURH, NXTH, CURX, NXTX) do {                                   \
        h8 vb0 = *(const h8*)(CURH + off_b0);                                   \
        h8 vb1 = *(const h8*)(CURH + off_b1);                                   \
        h8 vbx = *(const h8*)(CURX + off_b0);                                   \
        if (w == 0) {  /* stage x(t+1) into the other buffer */                 \
            int tc = t0 + jj + 1; tc = tc < TT ? tc : TT - 1;                   \
            h4 xv = *(const h4*)(xrow + (size_t)tc * (BB * II));                \
            *(h4*)(NXTX + off_xw) = xv;                                         \
        }                                                                       \
        f4 acc = __builtin_amdgcn_mfma_f32_16x16x32_f16(a2, vbx, biasv, 0,0,0); \
        acc = __builtin_amdgcn_mfma_f32_16x16x32_f16(a0, vb0, acc, 0, 0, 0);    \
        acc = __builtin_amdgcn_mfma_f32_16x16x32_f16(a1, vb1, acc, 0, 0, 0);    \
        float gi = fast_sigmoid(acc[0]);                                        \
        float gf = fast_sigmoid(acc[1]);                                        \
        float gg = fast_tanh(acc[2]);                                           \
        float go = fast_sigmoid(acc[3]);                                        \
        cst = fmaf(gf, cst, gi * gg);                                           \
        float hv = go * fast_tanh(cst);                                         \
        _Float16 h16 = (_Float16)hv;                                            \
        *(_Float16*)(NXTH + off_hw) = h16;                                      \
        hp.p2[jj >> 1][jj & 1] = h16;                                           \
        __syncthreads();                                                        \
    } while (0)

    for (int t4 = 0; t4 < T4; ++t4) {
        const int t0 = 4 * t4;
        union { h4 v4; h2 p2[2]; } hp;
        STEP(0, hA, hB, xA, xB);
        STEP(1, hB, hA, xB, xA);
        STEP(2, hA, hB, xA, xB);
        STEP(3, hB, hA, xB, xA);
        *sptr = hp.v4;                  // 8B fire-and-forget, acks amortized x4
        sptr += 512 * 64;
    }
#undef STEP
}

// ---------------- legacy one-wave-per-chain kernel (workspace fallback) ----------------
template <int STAGE, bool XF16>
__global__ __launch_bounds__(64, 1)
void lstm_wave(const float* __restrict__ x,
               const _Float16* __restrict__ xh,
               const float* __restrict__ Wih,
               const float* __restrict__ Whh,
               const float* __restrict__ bih,
               const float* __restrict__ bhh,
               const float* __restrict__ Wlin,
               const float* __restrict__ blin,
               float* __restrict__ out,
               float* __restrict__ lstm_out,
               _Float16* __restrict__ stage_f16)
{
    const int lane = threadIdx.x;
    const int c    = blockIdx.x;
    const int b    = c & (BB - 1);
    const int hd   = c >> 6;

    h2 whh[4][HIDN / 2];
    h2 wih[4][II / 2];
    float bias[4];
#pragma unroll
    for (int g = 0; g < 4; ++g) {
        const int r = hd * GG + g * HIDN + lane;
        const float4* p = (const float4*)(Whh + (size_t)r * HIDN);
#pragma unroll
        for (int q = 0; q < HIDN / 4; ++q) {
            float4 v = p[q];
            whh[g][2 * q]     = h2{ (_Float16)v.x, (_Float16)v.y };
            whh[g][2 * q + 1] = h2{ (_Float16)v.z, (_Float16)v.w };
        }
        const float4* pi = (const float4*)(Wih + (size_t)r * II);
#pragma unroll
        for (int q = 0; q < II / 4; ++q) {
            float4 v = pi[q];
            wih[g][2 * q]     = h2{ (_Float16)v.x, (_Float16)v.y };
            wih[g][2 * q + 1] = h2{ (_Float16)v.z, (_Float16)v.w };
        }
        bias[g] = bih[r] + bhh[r];
    }
    float wl = 0.0f, blv = 0.0f;
    if (STAGE == 2) { wl = Wlin[hd * HIDN + lane]; blv = blin[hd]; }

    __shared__ __align__(16) _Float16 hbuf[HIDN];
    hbuf[lane] = (_Float16)0.0f;

    float cst = 0.0f;

    const _Float16* xhp = xh + b * II;
    const float*    xfp = x + b * II;
    h2 xv[II / 2];
    auto load_x = [&](int t, h2* dst) {
        int tc = t < TT ? t : TT - 1;
        if (XF16) {
            const h8* p = (const h8*)(xhp + (size_t)tc * BB * II);
            union { h8 v; h2 p2[4]; } u0, u1;
            u0.v = p[0];
            u1.v = p[1];
#pragma unroll
            for (int i = 0; i < 4; ++i) { dst[i] = u0.p2[i]; dst[4 + i] = u1.p2[i]; }
        } else {
            const float4* p = (const float4*)(xfp + (size_t)tc * BB * II);
#pragma unroll
            for (int q = 0; q < 4; ++q) {
                float4 v = p[q];
                dst[2 * q]     = h2{ (_Float16)v.x, (_Float16)v.y };
                dst[2 * q + 1] = h2{ (_Float16)v.z, (_Float16)v.w };
            }
        }
    };
    load_x(0, xv);

    h4* sptr = (h4*)(stage_f16 + (size_t)c * 256 + lane * 4);

    for (int t4 = 0; t4 < T4; ++t4) {
        union { h4 v4; h2 p2[2]; } hp;
#pragma unroll
        for (int j = 0; j < 4; ++j) {
            const int t = t4 * 4 + j;
            h2 xn[II / 2];
            load_x(t + 1, xn);

            union { h8 v[8]; h2 p[32]; } hr;
#pragma unroll
            for (int q = 0; q < 8; ++q) hr.v[q] = ((const h8*)hbuf)[q];

            float z0 = bias[0], z1 = bias[1], z2 = bias[2], z3 = bias[3];
#pragma unroll
            for (int q = 0; q < HIDN / 2; ++q) {
                z0 = fdot2(whh[0][q], hr.p[q], z0);
                z1 = fdot2(whh[1][q], hr.p[q], z1);
                z2 = fdot2(whh[2][q], hr.p[q], z2);
                z3 = fdot2(whh[3][q], hr.p[q], z3);
            }
#pragma unroll
            for (int q = 0; q < II / 2; ++q) {
                z0 = fdot2(wih[0][q], xv[q], z0);
                z1 = fdot2(wih[1][q], xv[q], z1);
                z2 = fdot2(wih[2][q], xv[q], z2);
                z3 = fdot2(wih[3][q], xv[q], z3);
            }

            float gi = fast_sigmoid(z0);
            float gf = fast_sigmoid(z1);
            float gg = fast_tanh(z2);
            float go = fast_sigmoid(z3);

            cst = fmaf(gf, cst, gi * gg);
            float h = go * fast_tanh(cst);
            _Float16 h16 = (_Float16)h;

            hbuf[lane] = h16;
            hp.p2[j >> 1][j & 1] = h16;

            if (STAGE == 2) {
                atomicAdd(&lstm_out[((size_t)t * BB + b) * HIDN + lane], h);
                float p = h * wl;
                p += __shfl_down(p, 32, 64);
                p += __shfl_down(p, 16, 64);
                p += __shfl_down(p, 8, 64);
                p += __shfl_down(p, 4, 64);
                p += __shfl_down(p, 2, 64);
                p += __shfl_down(p, 1, 64);
                if (lane == 0) out[((size_t)t * BB + b) * HH + hd] = p + blv;
            }

#pragma unroll
            for (int q = 0; q < II / 2; ++q) xv[q] = xn[q];
        }
        if (STAGE == 1) {
            *sptr = hp.v4;
            sptr += 512 * 64;
        }
    }
}

// ---------------- pass 2a: lstm_out[t,b,k] = sum_hd h ----------------
__global__ __launch_bounds__(256)
void pass_lstm(const _Float16* __restrict__ stage, float* __restrict__ lstm_out)
{
    const int tid  = threadIdx.x;
    const int k    = tid & (HIDN - 1);
    const int q    = tid >> 6;
    const int b    = blockIdx.x & (BB - 1);
    const int tile = blockIdx.x >> 6;
    const h4* sp = (const h4*)stage;

#pragma unroll
    for (int g = 0; g < 4; ++g) {
        const int t4 = tile * 16 + q + 4 * g;
        float acc0 = 0.f, acc1 = 0.f, acc2 = 0.f, acc3 = 0.f;
#pragma unroll
        for (int hd = 0; hd < HH; ++hd) {
            h4 v = sp[((size_t)t4 * 512 + hd * 64 + b) * 64 + k];
            acc0 += (float)v.x; acc1 += (float)v.y;
            acc2 += (float)v.z; acc3 += (float)v.w;
        }
        const size_t t = (size_t)t4 * 4;
        lstm_out[((t + 0) * BB + b) * HIDN + k] = acc0;
        lstm_out[((t + 1) * BB + b) * HIDN + k] = acc1;
        lstm_out[((t + 2) * BB + b) * HIDN + k] = acc2;
        lstm_out[((t + 3) * BB + b) * HIDN + k] = acc3;
    }
}

// ---------------- pass 2b: out[t,b,hd] = dot(h, W_lin)+b_lin ----------------
__global__ __launch_bounds__(512)
void pass_out(const _Float16* __restrict__ stage,
              const float* __restrict__ Wlin,
              const float* __restrict__ blin,
              float* __restrict__ out)
{
    __shared__ float wls[GG * 2];
    const int tid = threadIdx.x;
    wls[tid] = Wlin[tid];
    __syncthreads();

    const int b  = tid >> 3;
    const int hd = tid & 7;
    const int c  = hd * 64 + b;
    const int t4 = blockIdx.x;
    const float bl = blin[hd];

    const h4* sp = (const h4*)stage + ((size_t)t4 * 512 + c) * 64;
    float a0 = 0.f, a1 = 0.f, a2 = 0.f, a3 = 0.f;
#pragma unroll 8
    for (int k = 0; k < HIDN; ++k) {
        h4 v = sp[k];
        float w = wls[hd * HIDN + k];
        a0 = fmaf((float)v.x, w, a0);
        a1 = fmaf((float)v.y, w, a1);
        a2 = fmaf((float)v.z, w, a2);
        a3 = fmaf((float)v.w, w, a3);
    }
    const size_t t = (size_t)t4 * 4;
    out[(t + 0) * 512 + tid] = a0 + bl;
    out[(t + 1) * 512 + tid] = a1 + bl;
    out[(t + 2) * 512 + tid] = a2 + bl;
    out[(t + 3) * 512 + tid] = a3 + bl;
}

extern "C" void kernel_launch(void* const* d_in, const int* in_sizes, int n_in,
                              void* d_out, int out_size, void* d_ws, size_t ws_size,
                              hipStream_t stream)
{
    const float* x    = (const float*)d_in[0];
    const float* Wih  = (const float*)d_in[1];
    const float* Whh  = (const float*)d_in[2];
    const float* bih  = (const float*)d_in[3];
    const float* bhh  = (const float*)d_in[4];
    const float* Wlin = (const float*)d_in[5];
    const float* blin = (const float*)d_in[6];

    float* out  = (float*)d_out;
    float* lstm = out + (size_t)TT * BB * HH;

    const size_t xbytes = (size_t)TT * BB * II * 2 + 4096;   // 4 MB + clamp slack
    const size_t slab16 = (size_t)TT * BB * HH * HIDN * 2;   // 134 MB

    const bool xf16 = ws_size >= xbytes;
    _Float16* xh = (_Float16*)d_ws;
    char* slabp  = (char*)d_ws + (xf16 ? xbytes : 0);
    size_t avail = ws_size - (xf16 ? xbytes : 0);
    const int mode = (avail >= slab16) ? 1 : 2;

    if (xf16) {
        int n4 = TT * BB * II / 4;
        cvt_x_kernel<<<(n4 + 255) / 256, 256, 0, stream>>>(x, xh, n4);
    }

    _Float16* sh = (_Float16*)slabp;

    if (mode == 1 && xf16) {
        // MFMA-batched path: 32 blocks x 1024 threads (head x 16-batch group)
        lstm_mfma<<<dim3(HH * 4), dim3(1024), 0, stream>>>(xh, Wih, Whh, bih, bhh, sh);
        pass_lstm<<<dim3(BB * 32), dim3(256), 0, stream>>>(sh, lstm);
        pass_out <<<dim3(T4), dim3(512), 0, stream>>>(sh, Wlin, blin, out);
    } else if (mode == 1) {
        dim3 grid(BB * HH), block(64);
        lstm_wave<1, false><<<grid, block, 0, stream>>>(x, xh, Wih, Whh, bih, bhh,
                                                        Wlin, blin, out, lstm, sh);
        pass_lstm<<<dim3(BB * 32), dim3(256), 0, stream>>>(sh, lstm);
        pass_out <<<dim3(T4), dim3(512), 0, stream>>>(sh, Wlin, blin, out);
    } else {
        hipMemsetAsync(lstm, 0, (size_t)TT * BB * HIDN * 4, stream);
        dim3 grid(BB * HH), block(64);
        if (xf16)
            lstm_wave<2, true><<<grid, block, 0, stream>>>(x, xh, Wih, Whh, bih, bhh,
                                                           Wlin, blin, out, lstm, sh);
        else
            lstm_wave<2, false><<<grid, block, 0, stream>>>(x, xh, Wih, Whh, bih, bhh,
                                                            Wlin, blin, out, lstm, sh);
    }
}

// Round 2
// 1098.394 us; speedup vs baseline: 1.0541x; 1.0541x over previous
//
#include <hip/hip_runtime.h>
#include <hip/hip_fp16.h>

#define TT   2048
#define BB   64
#define II   16
#define HH   8
#define HIDN 64
#define GG   256   // 4*HIDN
#define T4   (TT / 4)

typedef _Float16 h2 __attribute__((ext_vector_type(2)));
typedef _Float16 h4 __attribute__((ext_vector_type(4)));
typedef _Float16 h8 __attribute__((ext_vector_type(8)));
typedef float    f4 __attribute__((ext_vector_type(4)));

__device__ __forceinline__ float fdot2(h2 a, h2 b, float c) {
    return __builtin_amdgcn_fdot2(a, b, c, false);
}
__device__ __forceinline__ float fast_sigmoid(float z) {
    return __builtin_amdgcn_rcpf(1.0f + __expf(-z));
}
__device__ __forceinline__ float fast_tanh(float z) {
    return fmaf(2.0f, __builtin_amdgcn_rcpf(1.0f + __expf(-2.0f * z)), -1.0f);
}

// Swizzled LDS byte offset for element (b, u) of a [16 b][64 u] f16 tile.
// 16B granules along u; granule index XOR b spreads the 8 granule-starts of a
// wave's ds_read_b128 (lanes: b=lane&15, u=(lane>>4)*8) across all bank pairs.
__device__ __forceinline__ int lds_off(int b, int u) {
    return b * 128 + ((((u >> 3) ^ b) & 7) << 4) + (u & 7) * 2;
}
__device__ __forceinline__ h8 cvt8(const float* p) {
    float4 v0 = ((const float4*)p)[0];
    float4 v1 = ((const float4*)p)[1];
    return h8{(_Float16)v0.x, (_Float16)v0.y, (_Float16)v0.z, (_Float16)v0.w,
              (_Float16)v1.x, (_Float16)v1.y, (_Float16)v1.z, (_Float16)v1.w};
}

// LDS-visibility-only barrier: drain ds ops, do NOT drain vmcnt (keeps the
// x prefetch loads and the slab stores in flight across the barrier).
__device__ __forceinline__ void sync_lds() {
    asm volatile("s_waitcnt lgkmcnt(0)" ::: "memory");
    __builtin_amdgcn_s_barrier();
    asm volatile("" ::: "memory");
}

// ---------------- x -> f16 conversion (one-time, trivial) ----------------
__global__ void cvt_x_kernel(const float* __restrict__ x, _Float16* __restrict__ xh, int n4) {
    int i = blockIdx.x * blockDim.x + threadIdx.x;
    if (i < n4) {
        float4 v = ((const float4*)x)[i];
        ((h2*)xh)[2 * i]     = h2{ (_Float16)v.x, (_Float16)v.y };
        ((h2*)xh)[2 * i + 1] = h2{ (_Float16)v.z, (_Float16)v.w };
    }
}

// ---------------- main recurrent kernel: MFMA-batched chains ----------------
// One 1024-thread block per (head, 16-batch group); grid = 32. All 16 chains
// of the group share W_hh, so z = W.h is one (256x64)@(64x16) matmul/step on
// the matrix pipe. W rows are permuted to r' = 4*u_local + g so the C fragment
// of lane (hi=lane>>4, bl=lane&15) is exactly {z_i,z_f,z_g,z_o} of unit 4w+hi,
// batch bl -> gates stay 1-per-lane with ZERO post-MFMA shuffling.
//
// vs previous round (which was barrier/latency-bound at ~1265 cyc/step):
//  * x never goes through LDS: the x K-tile of A (a2) is zero for k>=16, so
//    the B-operand there is don't-care -> every lane global-loads its own 16B
//    x fragment, 4 steps ahead in a statically-rotated register pipeline.
//  * raw s_barrier + lgkmcnt(0)-only drain (no vmcnt(0) per step): x loads
//    and slab stores stay in flight across barriers.
//  * x-MFMA has register-only inputs -> issues off the critical path; the
//    post-barrier chain is ds_read h -> 2 MFMA -> gates.
__global__ __launch_bounds__(1024)
void lstm_mfma(const _Float16* __restrict__ xh,
               const float* __restrict__ Wih,
               const float* __restrict__ Whh,
               const float* __restrict__ bih,
               const float* __restrict__ bhh,
               _Float16* __restrict__ stage_f16)   // [t4][chain][unit][4] h4 (same as old)
{
    const int tid  = threadIdx.x;
    const int w    = tid >> 6;          // wave 0..15: owns units 4w..4w+3
    const int lane = tid & 63;
    const int hi   = lane >> 4;         // k-group / C row-group
    const int bl   = lane & 15;         // batch-in-group (C col)
    const int hd   = blockIdx.x >> 2;
    const int bg   = blockIdx.x & 3;
    const int ue   = 4 * w + hi;        // this lane's hidden unit (elementwise side)

    // ---- A fragments, row-permuted: frag row r' -> gate g=r'&3, unit 4w+(r'>>2)
    const int rA = hd * GG + (bl & 3) * HIDN + 4 * w + (bl >> 2);
    const float* pw = Whh + (size_t)rA * HIDN;
    h8 a0 = cvt8(pw + hi * 8);          // k = units (lane>>4)*8 + 0..7
    h8 a1 = cvt8(pw + 32 + hi * 8);     // k = units 32 + ...
    h8 a2{};                            // x-projection K-tile, zero-padded k>=16
    if (hi < 2) a2 = cvt8(Wih + (size_t)rA * II + hi * 8);

    // ---- bias as MFMA C-input (gate g = reg index, unit = ue, col = bl)
    f4 biasv;
#pragma unroll
    for (int g = 0; g < 4; ++g) {
        int r = hd * GG + g * HIDN + ue;
        biasv[g] = bih[r] + bhh[r];
    }

    // ---- LDS: h double-buffer only (4 KB) ----
    __shared__ __align__(16) char hA[2048];
    __shared__ __align__(16) char hB[2048];

    const int off_b0 = lds_off(bl, hi * 8);        // B frag, k-tile 0
    const int off_b1 = lds_off(bl, 32 + hi * 8);   // B frag, k-tile 1
    const int off_hw = lds_off(bl, ue);            // h(t) write slot

    // ---- per-lane x pointer + 4-deep register prefetch pipeline ----
    // lane (hi,bl) loads x[t][bg*16+bl][(hi&1)*8 .. +7]; for hi>=2 the value
    // is never used by the MFMA (A is zero there) but the load is harmless.
    const _Float16* xlane = xh + (size_t)(bg * 16 + bl) * II + (hi & 1) * 8;
    auto ldx = [&](int t) -> h8 {
        int tc = t < TT ? t : TT - 1;   // branchless clamp (prefetch overrun)
        return *(const h8*)(xlane + (size_t)tc * (BB * II));
    };

    // prologue: zero h(-1), prime x pipeline
    *(_Float16*)(hA + off_hw) = (_Float16)0.0f;
    h8 xp0 = ldx(0), xp1 = ldx(1), xp2 = ldx(2), xp3 = ldx(3);
    sync_lds();

    float cst = 0.0f;
    h4* sptr = (h4*)stage_f16 + (size_t)(hd * 64 + bg * 16 + bl) * 64 + ue;

#define STEP(jj, CURH, NXTH, XP) do {                                           \
        f4 acc = __builtin_amdgcn_mfma_f32_16x16x32_f16(a2, XP, biasv, 0,0,0);  \
        XP = ldx(t0 + jj + 4);          /* refill slot, consumed 4 steps on */  \
        h8 vb0 = *(const h8*)(CURH + off_b0);                                   \
        h8 vb1 = *(const h8*)(CURH + off_b1);                                   \
        acc = __builtin_amdgcn_mfma_f32_16x16x32_f16(a0, vb0, acc, 0, 0, 0);    \
        acc = __builtin_amdgcn_mfma_f32_16x16x32_f16(a1, vb1, acc, 0, 0, 0);    \
        float gi = fast_sigmoid(acc[0]);                                        \
        float gf = fast_sigmoid(acc[1]);                                        \
        float gg = fast_tanh(acc[2]);                                           \
        float go = fast_sigmoid(acc[3]);                                        \
        cst = fmaf(gf, cst, gi * gg);                                           \
        float hv = go * fast_tanh(cst);                                         \
        _Float16 h16 = (_Float16)hv;                                            \
        *(_Float16*)(NXTH + off_hw) = h16;                                      \
        hp.p2[jj >> 1][jj & 1] = h16;                                           \
        sync_lds();                                                             \
    } while (0)

    for (int t4 = 0; t4 < T4; ++t4) {
        const int t0 = 4 * t4;
        union { h4 v4; h2 p2[2]; } hp;
        STEP(0, hA, hB, xp0);
        STEP(1, hB, hA, xp1);
        STEP(2, hA, hB, xp2);
        STEP(3, hB, hA, xp3);
        *sptr = hp.v4;                  // 8B fire-and-forget, never drained in-loop
        sptr += 512 * 64;
    }
#undef STEP
}

// ---------------- legacy one-wave-per-chain kernel (workspace fallback) ----------------
template <int STAGE, bool XF16>
__global__ __launch_bounds__(64, 1)
void lstm_wave(const float* __restrict__ x,
               const _Float16* __restrict__ xh,
               const float* __restrict__ Wih,
               const float* __restrict__ Whh,
               const float* __restrict__ bih,
               const float* __restrict__ bhh,
               const float* __restrict__ Wlin,
               const float* __restrict__ blin,
               float* __restrict__ out,
               float* __restrict__ lstm_out,
               _Float16* __restrict__ stage_f16)
{
    const int lane = threadIdx.x;
    const int c    = blockIdx.x;
    const int b    = c & (BB - 1);
    const int hd   = c >> 6;

    h2 whh[4][HIDN / 2];
    h2 wih[4][II / 2];
    float bias[4];
#pragma unroll
    for (int g = 0; g < 4; ++g) {
        const int r = hd * GG + g * HIDN + lane;
        const float4* p = (const float4*)(Whh + (size_t)r * HIDN);
#pragma unroll
        for (int q = 0; q < HIDN / 4; ++q) {
            float4 v = p[q];
            whh[g][2 * q]     = h2{ (_Float16)v.x, (_Float16)v.y };
            whh[g][2 * q + 1] = h2{ (_Float16)v.z, (_Float16)v.w };
        }
        const float4* pi = (const float4*)(Wih + (size_t)r * II);
#pragma unroll
        for (int q = 0; q < II / 4; ++q) {
            float4 v = pi[q];
            wih[g][2 * q]     = h2{ (_Float16)v.x, (_Float16)v.y };
            wih[g][2 * q + 1] = h2{ (_Float16)v.z, (_Float16)v.w };
        }
        bias[g] = bih[r] + bhh[r];
    }
    float wl = 0.0f, blv = 0.0f;
    if (STAGE == 2) { wl = Wlin[hd * HIDN + lane]; blv = blin[hd]; }

    __shared__ __align__(16) _Float16 hbuf[HIDN];
    hbuf[lane] = (_Float16)0.0f;

    float cst = 0.0f;

    const _Float16* xhp = xh + b * II;
    const float*    xfp = x + b * II;
    h2 xv[II / 2];
    auto load_x = [&](int t, h2* dst) {
        int tc = t < TT ? t : TT - 1;
        if (XF16) {
            const h8* p = (const h8*)(xhp + (size_t)tc * BB * II);
            union { h8 v; h2 p2[4]; } u0, u1;
            u0.v = p[0];
            u1.v = p[1];
#pragma unroll
            for (int i = 0; i < 4; ++i) { dst[i] = u0.p2[i]; dst[4 + i] = u1.p2[i]; }
        } else {
            const float4* p = (const float4*)(xfp + (size_t)tc * BB * II);
#pragma unroll
            for (int q = 0; q < 4; ++q) {
                float4 v = p[q];
                dst[2 * q]     = h2{ (_Float16)v.x, (_Float16)v.y };
                dst[2 * q + 1] = h2{ (_Float16)v.z, (_Float16)v.w };
            }
        }
    };
    load_x(0, xv);

    h4* sptr = (h4*)(stage_f16 + (size_t)c * 256 + lane * 4);

    for (int t4 = 0; t4 < T4; ++t4) {
        union { h4 v4; h2 p2[2]; } hp;
#pragma unroll
        for (int j = 0; j < 4; ++j) {
            const int t = t4 * 4 + j;
            h2 xn[II / 2];
            load_x(t + 1, xn);

            union { h8 v[8]; h2 p[32]; } hr;
#pragma unroll
            for (int q = 0; q < 8; ++q) hr.v[q] = ((const h8*)hbuf)[q];

            float z0 = bias[0], z1 = bias[1], z2 = bias[2], z3 = bias[3];
#pragma unroll
            for (int q = 0; q < HIDN / 2; ++q) {
                z0 = fdot2(whh[0][q], hr.p[q], z0);
                z1 = fdot2(whh[1][q], hr.p[q], z1);
                z2 = fdot2(whh[2][q], hr.p[q], z2);
                z3 = fdot2(whh[3][q], hr.p[q], z3);
            }
#pragma unroll
            for (int q = 0; q < II / 2; ++q) {
                z0 = fdot2(wih[0][q], xv[q], z0);
                z1 = fdot2(wih[1][q], xv[q], z1);
                z2 = fdot2(wih[2][q], xv[q], z2);
                z3 = fdot2(wih[3][q], xv[q], z3);
            }

            float gi = fast_sigmoid(z0);
            float gf = fast_sigmoid(z1);
            float gg = fast_tanh(z2);
            float go = fast_sigmoid(z3);

            cst = fmaf(gf, cst, gi * gg);
            float h = go * fast_tanh(cst);
            _Float16 h16 = (_Float16)h;

            hbuf[lane] = h16;
            hp.p2[j >> 1][j & 1] = h16;

            if (STAGE == 2) {
                atomicAdd(&lstm_out[((size_t)t * BB + b) * HIDN + lane], h);
                float p = h * wl;
                p += __shfl_down(p, 32, 64);
                p += __shfl_down(p, 16, 64);
                p += __shfl_down(p, 8, 64);
                p += __shfl_down(p, 4, 64);
                p += __shfl_down(p, 2, 64);
                p += __shfl_down(p, 1, 64);
                if (lane == 0) out[((size_t)t * BB + b) * HH + hd] = p + blv;
            }

#pragma unroll
            for (int q = 0; q < II / 2; ++q) xv[q] = xn[q];
        }
        if (STAGE == 1) {
            *sptr = hp.v4;
            sptr += 512 * 64;
        }
    }
}

// ---------------- pass 2a: lstm_out[t,b,k] = sum_hd h ----------------
__global__ __launch_bounds__(256)
void pass_lstm(const _Float16* __restrict__ stage, float* __restrict__ lstm_out)
{
    const int tid  = threadIdx.x;
    const int k    = tid & (HIDN - 1);
    const int q    = tid >> 6;
    const int b    = blockIdx.x & (BB - 1);
    const int tile = blockIdx.x >> 6;
    const h4* sp = (const h4*)stage;

#pragma unroll
    for (int g = 0; g < 4; ++g) {
        const int t4 = tile * 16 + q + 4 * g;
        float acc0 = 0.f, acc1 = 0.f, acc2 = 0.f, acc3 = 0.f;
#pragma unroll
        for (int hd = 0; hd < HH; ++hd) {
            h4 v = sp[((size_t)t4 * 512 + hd * 64 + b) * 64 + k];
            acc0 += (float)v.x; acc1 += (float)v.y;
            acc2 += (float)v.z; acc3 += (float)v.w;
        }
        const size_t t = (size_t)t4 * 4;
        lstm_out[((t + 0) * BB + b) * HIDN + k] = acc0;
        lstm_out[((t + 1) * BB + b) * HIDN + k] = acc1;
        lstm_out[((t + 2) * BB + b) * HIDN + k] = acc2;
        lstm_out[((t + 3) * BB + b) * HIDN + k] = acc3;
    }
}

// ---------------- pass 2b: out[t,b,hd] = dot(h, W_lin)+b_lin ----------------
__global__ __launch_bounds__(512)
void pass_out(const _Float16* __restrict__ stage,
              const float* __restrict__ Wlin,
              const float* __restrict__ blin,
              float* __restrict__ out)
{
    __shared__ float wls[GG * 2];
    const int tid = threadIdx.x;
    wls[tid] = Wlin[tid];
    __syncthreads();

    const int b  = tid >> 3;
    const int hd = tid & 7;
    const int c  = hd * 64 + b;
    const int t4 = blockIdx.x;
    const float bl = blin[hd];

    const h4* sp = (const h4*)stage + ((size_t)t4 * 512 + c) * 64;
    float a0 = 0.f, a1 = 0.f, a2 = 0.f, a3 = 0.f;
#pragma unroll 8
    for (int k = 0; k < HIDN; ++k) {
        h4 v = sp[k];
        float w = wls[hd * HIDN + k];
        a0 = fmaf((float)v.x, w, a0);
        a1 = fmaf((float)v.y, w, a1);
        a2 = fmaf((float)v.z, w, a2);
        a3 = fmaf((float)v.w, w, a3);
    }
    const size_t t = (size_t)t4 * 4;
    out[(t + 0) * 512 + tid] = a0 + bl;
    out[(t + 1) * 512 + tid] = a1 + bl;
    out[(t + 2) * 512 + tid] = a2 + bl;
    out[(t + 3) * 512 + tid] = a3 + bl;
}

extern "C" void kernel_launch(void* const* d_in, const int* in_sizes, int n_in,
                              void* d_out, int out_size, void* d_ws, size_t ws_size,
                              hipStream_t stream)
{
    const float* x    = (const float*)d_in[0];
    const float* Wih  = (const float*)d_in[1];
    const float* Whh  = (const float*)d_in[2];
    const float* bih  = (const float*)d_in[3];
    const float* bhh  = (const float*)d_in[4];
    const float* Wlin = (const float*)d_in[5];
    const float* blin = (const float*)d_in[6];

    float* out  = (float*)d_out;
    float* lstm = out + (size_t)TT * BB * HH;

    const size_t xbytes = (size_t)TT * BB * II * 2 + 4096;   // 4 MB + clamp slack
    const size_t slab16 = (size_t)TT * BB * HH * HIDN * 2;   // 134 MB

    const bool xf16 = ws_size >= xbytes;
    _Float16* xh = (_Float16*)d_ws;
    char* slabp  = (char*)d_ws + (xf16 ? xbytes : 0);
    size_t avail = ws_size - (xf16 ? xbytes : 0);
    const int mode = (avail >= slab16) ? 1 : 2;

    if (xf16) {
        int n4 = TT * BB * II / 4;
        cvt_x_kernel<<<(n4 + 255) / 256, 256, 0, stream>>>(x, xh, n4);
    }

    _Float16* sh = (_Float16*)slabp;

    if (mode == 1 && xf16) {
        // MFMA-batched path: 32 blocks x 1024 threads (head x 16-batch group)
        lstm_mfma<<<dim3(HH * 4), dim3(1024), 0, stream>>>(xh, Wih, Whh, bih, bhh, sh);
        pass_lstm<<<dim3(BB * 32), dim3(256), 0, stream>>>(sh, lstm);
        pass_out <<<dim3(T4), dim3(512), 0, stream>>>(sh, Wlin, blin, out);
    } else if (mode == 1) {
        dim3 grid(BB * HH), block(64);
        lstm_wave<1, false><<<grid, block, 0, stream>>>(x, xh, Wih, Whh, bih, bhh,
                                                        Wlin, blin, out, lstm, sh);
        pass_lstm<<<dim3(BB * 32), dim3(256), 0, stream>>>(sh, lstm);
        pass_out <<<dim3(T4), dim3(512), 0, stream>>>(sh, Wlin, blin, out);
    } else {
        hipMemsetAsync(lstm, 0, (size_t)TT * BB * HIDN * 4, stream);
        dim3 grid(BB * HH), block(64);
        if (xf16)
            lstm_wave<2, true><<<grid, block, 0, stream>>>(x, xh, Wih, Whh, bih, bhh,
                                                           Wlin, blin, out, lstm, sh);
        else
            lstm_wave<2, false><<<grid, block, 0, stream>>>(x, xh, Wih, Whh, bih, bhh,
                                                            Wlin, blin, out, lstm, sh);
    }
}